// Round 16
// baseline (314.290 us; speedup 1.0000x reference)
//
#include <hip/hip_runtime.h>
#include <hip/hip_bf16.h>

#define D_FEAT 256
#define EPS 1e-12f

// Build CSR row_ptr from sorted COO row array.
__global__ void build_row_ptr_kernel(const int* __restrict__ row,
                                     int* __restrict__ row_ptr,
                                     int E, int N) {
    int e = blockIdx.x * blockDim.x + threadIdx.x;
    if (e > E) return;
    int curr = (e == E) ? N : row[e];
    int prev = (e == 0) ? -1 : row[e - 1];
    for (int r = prev + 1; r <= curr; ++r) row_ptr[r] = e;
}

// Quantize fp32 rows -> biased uint8 (q = round(v/scale)+128) + per-row scale.
__global__ __launch_bounds__(256) void quant_rows_kernel(
    const float* __restrict__ in,
    unsigned char* __restrict__ q,
    float* __restrict__ s,
    int n_rows)
{
    const int wave = threadIdx.x >> 6, lane = threadIdx.x & 63;
    const int r = blockIdx.x * 4 + wave;
    if (r >= n_rows) return;
    const long idx = (long)r * 64 + lane;
    const float4 f = ((const float4*)in)[idx];
    float m = fmaxf(fmaxf(fabsf(f.x), fabsf(f.y)), fmaxf(fabsf(f.z), fabsf(f.w)));
    #pragma unroll
    for (int off = 32; off; off >>= 1) m = fmaxf(m, __shfl_xor(m, off));
    const float mg  = fmaxf(m, 1e-30f);
    const float inv = 127.0f / mg;
    const unsigned int u0 = (unsigned int)(int)rintf(fmaf(f.x, inv, 128.0f));
    const unsigned int u1 = (unsigned int)(int)rintf(fmaf(f.y, inv, 128.0f));
    const unsigned int u2 = (unsigned int)(int)rintf(fmaf(f.z, inv, 128.0f));
    const unsigned int u3 = (unsigned int)(int)rintf(fmaf(f.w, inv, 128.0f));
    ((unsigned int*)q)[idx] = u0 | (u1 << 8) | (u2 << 16) | (u3 << 24);
    if (lane == 0) s[r] = mg * (1.0f / 127.0f);
}

// L0: SpMM over int8 table, 4 edges per dwordx4 load.
// lane l: edge sub-slot eg = l>>4, dim block dl = l&15 (dims dl*16..+16).
__global__ __launch_bounds__(256) void spmm_q_kernel(
    const unsigned char* __restrict__ q_in,
    const float* __restrict__ s_in,
    const float* __restrict__ vals,
    const int*   __restrict__ col,
    const int*   __restrict__ row_ptr,
    unsigned char* __restrict__ q_out,
    float* __restrict__ s_out,
    unsigned short* __restrict__ q4_out,
    float* __restrict__ s4_out,
    int n_nodes)
{
    __shared__ float    ldsw[4][64];
    __shared__ unsigned ldso[4][64];

    const int wave = threadIdx.x >> 6, lane = threadIdx.x & 63;
    const int r = blockIdx.x * 4 + wave;
    if (r >= n_nodes) return;

    const int start = row_ptr[r];
    const int end   = row_ptr[r + 1];
    const int eg = lane >> 4;
    const int dl = lane & 15;
    const unsigned dlb = (unsigned)dl * 16u;

    float acc[16];
    #pragma unroll
    for (int k = 0; k < 16; ++k) acc[k] = 0.f;
    float wsum = 0.f;   // total over lanes = 16 * sum(w)

    for (int base = start; base < end; base += 64) {
        const int n = min(64, end - base);
        float    w   = 0.f;
        unsigned off = 0;
        if (lane < n) {
            const int c = col[base + lane];
            w   = vals[base + lane] * s_in[c];
            off = (unsigned)c << 8;          // c * 256 bytes
        }
        ldsw[wave][lane] = w;    // zero-filled tail: w=0 gathers row 0, adds 0
        ldso[wave][lane] = off;
        const int ng = (n + 3) >> 2;
        #pragma unroll 4
        for (int jg = 0; jg < ng; ++jg) {
            const int slot = (jg << 2) | eg;
            const float    wj   = ldsw[wave][slot];
            const unsigned voff = ldso[wave][slot] + dlb;
            const uint4 g = *(const uint4*)(q_in + voff);
            wsum += wj;
            acc[0]  += wj * (float)( g.x         & 0xffu);
            acc[1]  += wj * (float)((g.x >>  8u) & 0xffu);
            acc[2]  += wj * (float)((g.x >> 16u) & 0xffu);
            acc[3]  += wj * (float)( g.x >> 24u);
            acc[4]  += wj * (float)( g.y         & 0xffu);
            acc[5]  += wj * (float)((g.y >>  8u) & 0xffu);
            acc[6]  += wj * (float)((g.y >> 16u) & 0xffu);
            acc[7]  += wj * (float)( g.y >> 24u);
            acc[8]  += wj * (float)( g.z         & 0xffu);
            acc[9]  += wj * (float)((g.z >>  8u) & 0xffu);
            acc[10] += wj * (float)((g.z >> 16u) & 0xffu);
            acc[11] += wj * (float)( g.z >> 24u);
            acc[12] += wj * (float)( g.w         & 0xffu);
            acc[13] += wj * (float)((g.w >>  8u) & 0xffu);
            acc[14] += wj * (float)((g.w >> 16u) & 0xffu);
            acc[15] += wj * (float)( g.w >> 24u);
        }
    }

    #pragma unroll
    for (int k = 0; k < 16; ++k) {
        acc[k] += __shfl_xor(acc[k], 16);
        acc[k] += __shfl_xor(acc[k], 32);
    }
    float ws = wsum;
    #pragma unroll
    for (int o = 32; o; o >>= 1) ws += __shfl_xor(ws, o);
    const float bias = 8.0f * ws;          // = 128 * (ws/16), exact

    float s = 0.f;
    #pragma unroll
    for (int k = 0; k < 16; ++k) { acc[k] -= bias; s += acc[k] * acc[k]; }
    #pragma unroll
    for (int o = 8; o; o >>= 1) s += __shfl_xor(s, o);

    const float sc = 1.0f / fmaxf(sqrtf(s), EPS);
    float m = 0.f;
    #pragma unroll
    for (int k = 0; k < 16; ++k) { acc[k] *= sc; m = fmaxf(m, fabsf(acc[k])); }
    #pragma unroll
    for (int o = 8; o; o >>= 1) m = fmaxf(m, __shfl_xor(m, o));
    const float mg = fmaxf(m, 1e-30f);

    float h0, h1, h2, h3;
    if      (eg == 0) { h0 = acc[0];  h1 = acc[1];  h2 = acc[2];  h3 = acc[3];  }
    else if (eg == 1) { h0 = acc[4];  h1 = acc[5];  h2 = acc[6];  h3 = acc[7];  }
    else if (eg == 2) { h0 = acc[8];  h1 = acc[9];  h2 = acc[10]; h3 = acc[11]; }
    else              { h0 = acc[12]; h1 = acc[13]; h2 = acc[14]; h3 = acc[15]; }

    const long pidx = (long)r * 64 + (dl << 2) + eg;   // natural dword layout

    const float inv = 127.0f / mg;
    const unsigned u0 = (unsigned)(int)rintf(fmaf(h0, inv, 128.0f));
    const unsigned u1 = (unsigned)(int)rintf(fmaf(h1, inv, 128.0f));
    const unsigned u2 = (unsigned)(int)rintf(fmaf(h2, inv, 128.0f));
    const unsigned u3 = (unsigned)(int)rintf(fmaf(h3, inv, 128.0f));
    ((unsigned*)q_out)[pidx] = u0 | (u1 << 8) | (u2 << 16) | (u3 << 24);
    if (lane == 0) s_out[r] = mg * (1.0f / 127.0f);

    const float inv4 = 7.0f / mg;
    const unsigned n0 = ((unsigned)((int)rintf(h0 * inv4) + 8)) & 15u;
    const unsigned n1 = ((unsigned)((int)rintf(h1 * inv4) + 8)) & 15u;
    const unsigned n2 = ((unsigned)((int)rintf(h2 * inv4) + 8)) & 15u;
    const unsigned n3 = ((unsigned)((int)rintf(h3 * inv4) + 8)) & 15u;
    q4_out[pidx] = (unsigned short)(n0 | (n1 << 4) | (n2 << 8) | (n3 << 12));
    if (lane == 0) s4_out[r] = mg * (1.0f / 7.0f);
}

// L1/L2: SpMM over packed-int4 table, 4 edges per dwordx2 load.
// DIRECT nibble decode (exact, no back-substitution chain):
//   lo = g & 0x0F0F0F0F -> even nibbles d0,d2,d4,d6 as bytes
//   hi = (g>>4) & 0x0F0F0F0F -> odd nibbles d1,d3,d5,d7 as bytes
// v_cvt_f32_ubyteN extracts bytes for free.
__global__ __launch_bounds__(256) void spmm_q4_kernel(
    const unsigned char* __restrict__ q4_in,
    const float* __restrict__ s4_in,
    const float* __restrict__ vals,
    const int*   __restrict__ col,
    const int*   __restrict__ row_ptr,
    unsigned char* __restrict__ q_out,
    float* __restrict__ s_out,
    unsigned short* __restrict__ q4_out,
    float* __restrict__ s4_out,
    const unsigned char* __restrict__ q0p, const float* __restrict__ s0p,
    const unsigned char* __restrict__ q1p, const float* __restrict__ s1p,
    const unsigned char* __restrict__ q2p, const float* __restrict__ s2p,
    float* __restrict__ out,
    int n_nodes, int mode)
{
    __shared__ float    ldsw[4][64];
    __shared__ unsigned ldso[4][64];

    const int wave = threadIdx.x >> 6, lane = threadIdx.x & 63;
    const int r = blockIdx.x * 4 + wave;
    if (r >= n_nodes) return;

    const int start = row_ptr[r];
    const int end   = row_ptr[r + 1];
    const int eg = lane >> 4;
    const int dl = lane & 15;
    const unsigned dlb = (unsigned)dl * 8u;

    float acc[16];
    #pragma unroll
    for (int k = 0; k < 16; ++k) acc[k] = 0.f;
    float wsum = 0.f;

    for (int base = start; base < end; base += 64) {
        const int n = min(64, end - base);
        float    w   = 0.f;
        unsigned off = 0;
        if (lane < n) {
            const int c = col[base + lane];
            w   = vals[base + lane] * s4_in[c];
            off = (unsigned)c << 7;          // c * 128 bytes
        }
        ldsw[wave][lane] = w;
        ldso[wave][lane] = off;
        const int ng = (n + 3) >> 2;
        #pragma unroll 2
        for (int jg = 0; jg < ng; ++jg) {
            const int slot = (jg << 2) | eg;
            const float    wj   = ldsw[wave][slot];
            const unsigned voff = ldso[wave][slot] + dlb;
            const uint2 g = *(const uint2*)(q4_in + voff);
            const unsigned lox = g.x & 0x0F0F0F0Fu;
            const unsigned hix = (g.x >> 4u) & 0x0F0F0F0Fu;
            const unsigned loy = g.y & 0x0F0F0F0Fu;
            const unsigned hiy = (g.y >> 4u) & 0x0F0F0F0Fu;
            wsum += wj;
            acc[0]  += wj * (float)( lox         & 0xffu);
            acc[1]  += wj * (float)( hix         & 0xffu);
            acc[2]  += wj * (float)((lox >>  8u) & 0xffu);
            acc[3]  += wj * (float)((hix >>  8u) & 0xffu);
            acc[4]  += wj * (float)((lox >> 16u) & 0xffu);
            acc[5]  += wj * (float)((hix >> 16u) & 0xffu);
            acc[6]  += wj * (float)( lox >> 24u);
            acc[7]  += wj * (float)( hix >> 24u);
            acc[8]  += wj * (float)( loy         & 0xffu);
            acc[9]  += wj * (float)( hiy         & 0xffu);
            acc[10] += wj * (float)((loy >>  8u) & 0xffu);
            acc[11] += wj * (float)((hiy >>  8u) & 0xffu);
            acc[12] += wj * (float)((loy >> 16u) & 0xffu);
            acc[13] += wj * (float)((hiy >> 16u) & 0xffu);
            acc[14] += wj * (float)( loy >> 24u);
            acc[15] += wj * (float)( hiy >> 24u);
        }
    }

    #pragma unroll
    for (int k = 0; k < 16; ++k) {
        acc[k] += __shfl_xor(acc[k], 16);
        acc[k] += __shfl_xor(acc[k], 32);
    }
    float ws = wsum;
    #pragma unroll
    for (int o = 32; o; o >>= 1) ws += __shfl_xor(ws, o);
    const float bias = 0.5f * ws;    // = 8 * (ws/16), exact

    float s = 0.f;
    #pragma unroll
    for (int k = 0; k < 16; ++k) { acc[k] -= bias; s += acc[k] * acc[k]; }
    #pragma unroll
    for (int o = 8; o; o >>= 1) s += __shfl_xor(s, o);

    const float sc = 1.0f / fmaxf(sqrtf(s), EPS);
    float m = 0.f;
    #pragma unroll
    for (int k = 0; k < 16; ++k) { acc[k] *= sc; m = fmaxf(m, fabsf(acc[k])); }
    #pragma unroll
    for (int o = 8; o; o >>= 1) m = fmaxf(m, __shfl_xor(m, o));
    const float mg = fmaxf(m, 1e-30f);

    float h0, h1, h2, h3;
    if      (eg == 0) { h0 = acc[0];  h1 = acc[1];  h2 = acc[2];  h3 = acc[3];  }
    else if (eg == 1) { h0 = acc[4];  h1 = acc[5];  h2 = acc[6];  h3 = acc[7];  }
    else if (eg == 2) { h0 = acc[8];  h1 = acc[9];  h2 = acc[10]; h3 = acc[11]; }
    else              { h0 = acc[12]; h1 = acc[13]; h2 = acc[14]; h3 = acc[15]; }

    const long pidx = (long)r * 64 + (dl << 2) + eg;   // natural dword layout

    if (mode < 2) {
        const float inv = 127.0f / mg;
        const unsigned u0 = (unsigned)(int)rintf(fmaf(h0, inv, 128.0f));
        const unsigned u1 = (unsigned)(int)rintf(fmaf(h1, inv, 128.0f));
        const unsigned u2 = (unsigned)(int)rintf(fmaf(h2, inv, 128.0f));
        const unsigned u3 = (unsigned)(int)rintf(fmaf(h3, inv, 128.0f));
        ((unsigned*)q_out)[pidx] = u0 | (u1 << 8) | (u2 << 16) | (u3 << 24);
        if (lane == 0) s_out[r] = mg * (1.0f / 127.0f);

        const float inv4 = 7.0f / mg;
        const unsigned n0 = ((unsigned)((int)rintf(h0 * inv4) + 8)) & 15u;
        const unsigned n1 = ((unsigned)((int)rintf(h1 * inv4) + 8)) & 15u;
        const unsigned n2 = ((unsigned)((int)rintf(h2 * inv4) + 8)) & 15u;
        const unsigned n3 = ((unsigned)((int)rintf(h3 * inv4) + 8)) & 15u;
        q4_out[pidx] = (unsigned short)(n0 | (n1 << 4) | (n2 << 8) | (n3 << 12));
        if (lane == 0) s4_out[r] = mg * (1.0f / 7.0f);
    } else {
        const unsigned g0 = ((const unsigned*)q0p)[pidx];
        const unsigned g1 = ((const unsigned*)q1p)[pidx];
        const unsigned g2 = ((const unsigned*)q2p)[pidx];
        const float sc0 = s0p[r], sc1 = s1p[r], sc2 = s2p[r];
        float4 o;
        o.x = 0.25f * (((float)(g0 & 0xff)         - 128.f) * sc0
                     + ((float)(g1 & 0xff)         - 128.f) * sc1
                     + ((float)(g2 & 0xff)         - 128.f) * sc2 + h0);
        o.y = 0.25f * (((float)((g0 >> 8) & 0xff)  - 128.f) * sc0
                     + ((float)((g1 >> 8) & 0xff)  - 128.f) * sc1
                     + ((float)((g2 >> 8) & 0xff)  - 128.f) * sc2 + h1);
        o.z = 0.25f * (((float)((g0 >> 16) & 0xff) - 128.f) * sc0
                     + ((float)((g1 >> 16) & 0xff) - 128.f) * sc1
                     + ((float)((g2 >> 16) & 0xff) - 128.f) * sc2 + h2);
        o.w = 0.25f * (((float)(g0 >> 24)          - 128.f) * sc0
                     + ((float)(g1 >> 24)          - 128.f) * sc1
                     + ((float)(g2 >> 24)          - 128.f) * sc2 + h3);
        ((float4*)out)[pidx] = o;
    }
}

extern "C" void kernel_launch(void* const* d_in, const int* in_sizes, int n_in,
                              void* d_out, int out_size, void* d_ws, size_t ws_size,
                              hipStream_t stream) {
    const float* x    = (const float*)d_in[0];
    const float* vals = (const float*)d_in[1];
    const int*   row  = (const int*)d_in[2];
    const int*   col  = (const int*)d_in[3];
    float* out = (float*)d_out;

    const int N = in_sizes[0] / D_FEAT;   // 100000
    const int E = in_sizes[1];            // 1600000

    auto align1k = [](size_t v) { return (v + 1023) & ~(size_t)1023; };
    const size_t rp_bytes = align1k((size_t)(N + 1) * sizeof(int));
    const size_t qbytes   = align1k((size_t)N * D_FEAT);
    const size_t q4bytes  = align1k((size_t)N * D_FEAT / 2);
    const size_t sbytes   = align1k((size_t)N * sizeof(float));
    char* ws = (char*)d_ws;
    int*            row_ptr = (int*)ws;            ws += rp_bytes;
    unsigned char*  xq  = (unsigned char*)ws;      ws += qbytes;
    float*          sx  = (float*)ws;              ws += sbytes;
    unsigned char*  q1  = (unsigned char*)ws;      ws += qbytes;
    float*          s1  = (float*)ws;              ws += sbytes;
    unsigned char*  q2  = (unsigned char*)ws;      ws += qbytes;
    float*          s2  = (float*)ws;              ws += sbytes;
    unsigned char*  q1n = (unsigned char*)ws;      ws += q4bytes;
    float*          s1n = (float*)ws;              ws += sbytes;
    unsigned char*  q2n = (unsigned char*)ws;      ws += q4bytes;
    float*          s2n = (float*)ws;

    {
        const int threads = 256;
        const int blocks = (E + 1 + threads - 1) / threads;
        build_row_ptr_kernel<<<blocks, threads, 0, stream>>>(row, row_ptr, E, N);
    }

    const int blocks = (N + 3) / 4;

    quant_rows_kernel<<<blocks, 256, 0, stream>>>(x, xq, sx, N);

    // L0 (int8 gather, 4 edges/load): h1 -> q1/s1 + q1n/s1n
    spmm_q_kernel<<<blocks, 256, 0, stream>>>(xq, sx, vals, col, row_ptr,
                                              q1, s1, (unsigned short*)q1n, s1n, N);
    // L1 (int4 gather, 4 edges/load): h2 -> q2/s2 + q2n/s2n
    spmm_q4_kernel<<<blocks, 256, 0, stream>>>(q1n, s1n, vals, col, row_ptr,
                                               q2, s2, (unsigned short*)q2n, s2n,
                                               xq, sx, q1, s1, q2, s2, out, N, 0);
    // L2 (int4 gather + combine): out = 0.25*(x + h1 + h2 + h3)
    spmm_q4_kernel<<<blocks, 256, 0, stream>>>(q2n, s2n, vals, col, row_ptr,
                                               q2, s2, (unsigned short*)q2n, s2n,
                                               xq, sx, q1, s1, q2, s2, out, N, 2);
}

// Round 17
// 253.036 us; speedup vs baseline: 1.2421x; 1.2421x over previous
//
#include <hip/hip_runtime.h>
#include <hip/hip_bf16.h>

#define D_FEAT 256
#define EPS 1e-12f

// Build CSR row_ptr from sorted COO row array.
__global__ void build_row_ptr_kernel(const int* __restrict__ row,
                                     int* __restrict__ row_ptr,
                                     int E, int N) {
    int e = blockIdx.x * blockDim.x + threadIdx.x;
    if (e > E) return;
    int curr = (e == E) ? N : row[e];
    int prev = (e == 0) ? -1 : row[e - 1];
    for (int r = prev + 1; r <= curr; ++r) row_ptr[r] = e;
}

// Quantize fp32 rows -> biased uint8 (q = round(v/scale)+128) + per-row scale.
__global__ __launch_bounds__(256) void quant_rows_kernel(
    const float* __restrict__ in,
    unsigned char* __restrict__ q,
    float* __restrict__ s,
    int n_rows)
{
    const int wave = threadIdx.x >> 6, lane = threadIdx.x & 63;
    const int r = blockIdx.x * 4 + wave;
    if (r >= n_rows) return;
    const long idx = (long)r * 64 + lane;
    const float4 f = ((const float4*)in)[idx];
    float m = fmaxf(fmaxf(fabsf(f.x), fabsf(f.y)), fmaxf(fabsf(f.z), fabsf(f.w)));
    #pragma unroll
    for (int off = 32; off; off >>= 1) m = fmaxf(m, __shfl_xor(m, off));
    const float mg  = fmaxf(m, 1e-30f);
    const float inv = 127.0f / mg;
    const unsigned int u0 = (unsigned int)(int)rintf(fmaf(f.x, inv, 128.0f));
    const unsigned int u1 = (unsigned int)(int)rintf(fmaf(f.y, inv, 128.0f));
    const unsigned int u2 = (unsigned int)(int)rintf(fmaf(f.z, inv, 128.0f));
    const unsigned int u3 = (unsigned int)(int)rintf(fmaf(f.w, inv, 128.0f));
    ((unsigned int*)q)[idx] = u0 | (u1 << 8) | (u2 << 16) | (u3 << 24);
    if (lane == 0) s[r] = mg * (1.0f / 127.0f);
}

// L0: SpMM over int8 table + L2 normalize; writes int8 AND packed-int4 h.
// One wave per row. Edge metadata (w, byte-offset) fused into one uint2 LDS
// entry -> single ds_read_b64 broadcast per edge. Gather: 32-bit voffset +
// uniform base (saddr form). Inner loop unrolled x8 for outstanding gathers.
__global__ __launch_bounds__(256) void spmm_q_kernel(
    const unsigned char* __restrict__ q_in,
    const float* __restrict__ s_in,
    const float* __restrict__ vals,
    const int*   __restrict__ col,
    const int*   __restrict__ row_ptr,
    unsigned char* __restrict__ q_out,
    float* __restrict__ s_out,
    unsigned short* __restrict__ q4_out,
    float* __restrict__ s4_out,
    int n_nodes)
{
    __shared__ uint2 ldsm[4][64];   // .x = bits(w), .y = byte offset

    const int wave = threadIdx.x >> 6, lane = threadIdx.x & 63;
    const int r = blockIdx.x * 4 + wave;
    if (r >= n_nodes) return;

    const int start = row_ptr[r];
    const int end   = row_ptr[r + 1];
    const unsigned lane4 = (unsigned)lane * 4u;

    float ax = 0.f, ay = 0.f, az = 0.f, aw = 0.f;
    float wsum = 0.f;   // wave-uniform (broadcast adds)

    for (int base = start; base < end; base += 64) {
        const int n = min(64, end - base);
        float    w   = 0.f;
        unsigned off = 0;
        if (lane < n) {
            const int c = col[base + lane];
            w   = vals[base + lane] * s_in[c];
            off = (unsigned)c << 8;          // c * 256 bytes
        }
        ldsm[wave][lane] = make_uint2(__float_as_uint(w), off);
        #pragma unroll 8
        for (int j = 0; j < n; ++j) {
            const uint2    mj   = ldsm[wave][j];              // ds_read_b64 broadcast
            const float    wj   = __uint_as_float(mj.x);
            const unsigned voff = mj.y + lane4;
            const unsigned int g = *(const unsigned int*)(q_in + voff);
            wsum += wj;
            ax += wj * (float)(g & 0xff);         ay += wj * (float)((g >> 8) & 0xff);
            az += wj * (float)((g >> 16) & 0xff); aw += wj * (float)(g >> 24);
        }
    }

    const float bias = 128.0f * wsum;   // wsum already uniform
    const float px = ax - bias, py = ay - bias, pz = az - bias, pw = aw - bias;

    float s = px * px + py * py + pz * pz + pw * pw;
    #pragma unroll
    for (int off = 32; off; off >>= 1) s += __shfl_xor(s, off);

    const float sc = 1.0f / fmaxf(sqrtf(s), EPS);
    const float hx = px * sc, hy = py * sc, hz = pz * sc, hw = pw * sc;

    const long idx = (long)r * 64 + lane;

    float m = fmaxf(fmaxf(fabsf(hx), fabsf(hy)), fmaxf(fabsf(hz), fabsf(hw)));
    #pragma unroll
    for (int off = 32; off; off >>= 1) m = fmaxf(m, __shfl_xor(m, off));
    const float mg  = fmaxf(m, 1e-30f);
    const float inv = 127.0f / mg;
    const unsigned int u0 = (unsigned int)(int)rintf(fmaf(hx, inv, 128.0f));
    const unsigned int u1 = (unsigned int)(int)rintf(fmaf(hy, inv, 128.0f));
    const unsigned int u2 = (unsigned int)(int)rintf(fmaf(hz, inv, 128.0f));
    const unsigned int u3 = (unsigned int)(int)rintf(fmaf(hw, inv, 128.0f));
    ((unsigned int*)q_out)[idx] = u0 | (u1 << 8) | (u2 << 16) | (u3 << 24);
    if (lane == 0) s_out[r] = mg * (1.0f / 127.0f);

    const float inv4 = 7.0f / mg;
    const unsigned int n0 = ((unsigned int)((int)rintf(hx * inv4) + 8)) & 15u;
    const unsigned int n1 = ((unsigned int)((int)rintf(hy * inv4) + 8)) & 15u;
    const unsigned int n2 = ((unsigned int)((int)rintf(hz * inv4) + 8)) & 15u;
    const unsigned int n3 = ((unsigned int)((int)rintf(hw * inv4) + 8)) & 15u;
    q4_out[idx] = (unsigned short)(n0 | (n1 << 4) | (n2 << 8) | (n3 << 12));
    if (lane == 0) s4_out[r] = mg * (1.0f / 7.0f);
}

// L1/L2: SpMM over packed-int4 table (2B/lane), fused-LDS metadata,
// byte-cvt mixed-sum decode (4-deep back-substitution, verified at R12):
//   SA=sum w*(n0+16n1), SB=sum w*(n1+16n2), SC=sum w*(n2+16n3), SD=sum w*n3
//   A3=SD, A2=SC-16A3, A1=SB-16A2, A0=SA-16A1.
// mode 0/1: + normalize + write int8 and int4 h tables
// mode 2:   + normalize + combine: out = 0.25*(dq(q0)+dq(q1)+dq(q2)+h)
__global__ __launch_bounds__(256) void spmm_q4_kernel(
    const unsigned char* __restrict__ q4_in,   // packed int4 rows, 128B stride
    const float* __restrict__ s4_in,
    const float* __restrict__ vals,
    const int*   __restrict__ col,
    const int*   __restrict__ row_ptr,
    unsigned char* __restrict__ q_out,
    float* __restrict__ s_out,
    unsigned short* __restrict__ q4_out,
    float* __restrict__ s4_out,
    const unsigned char* __restrict__ q0p, const float* __restrict__ s0p,
    const unsigned char* __restrict__ q1p, const float* __restrict__ s1p,
    const unsigned char* __restrict__ q2p, const float* __restrict__ s2p,
    float* __restrict__ out,
    int n_nodes, int mode)
{
    __shared__ uint2 ldsm[4][64];   // .x = bits(w), .y = byte offset

    const int wave = threadIdx.x >> 6, lane = threadIdx.x & 63;
    const int r = blockIdx.x * 4 + wave;
    if (r >= n_nodes) return;

    const int start = row_ptr[r];
    const int end   = row_ptr[r + 1];
    const unsigned lane2 = (unsigned)lane * 2u;

    float sa = 0.f, sb = 0.f, sc4 = 0.f, sd = 0.f;
    float wsum = 0.f;   // wave-uniform

    for (int base = start; base < end; base += 64) {
        const int n = min(64, end - base);
        float    w   = 0.f;
        unsigned off = 0;
        if (lane < n) {
            const int c = col[base + lane];
            w   = vals[base + lane] * s4_in[c];
            off = (unsigned)c << 7;          // c * 128 bytes
        }
        ldsm[wave][lane] = make_uint2(__float_as_uint(w), off);
        #pragma unroll 8
        for (int j = 0; j < n; ++j) {
            const uint2    mj   = ldsm[wave][j];              // ds_read_b64 broadcast
            const float    wj   = __uint_as_float(mj.x);
            const unsigned voff = mj.y + lane2;
            const unsigned int g = *(const unsigned short*)(q4_in + voff);
            wsum += wj;
            sa  += wj * (float)(g & 0xffu);
            sb  += wj * (float)((g >> 4) & 0xffu);
            sc4 += wj * (float)((g >> 8) & 0xffu);
            sd  += wj * (float)(g >> 12);
        }
    }

    // separate the mixed accumulators (exact, 4-deep — verified at R12)
    const float a3 = sd;
    const float a2 = sc4 - 16.0f * a3;
    const float a1 = sb  - 16.0f * a2;
    const float a0 = sa  - 16.0f * a1;

    const float bias = 8.0f * wsum;   // int4 bias center, wsum uniform

    const float px = a0 - bias, py = a1 - bias, pz = a2 - bias, pw = a3 - bias;

    float s = px * px + py * py + pz * pz + pw * pw;
    #pragma unroll
    for (int off = 32; off; off >>= 1) s += __shfl_xor(s, off);

    const float sc = 1.0f / fmaxf(sqrtf(s), EPS);
    const float hx = px * sc, hy = py * sc, hz = pz * sc, hw = pw * sc;

    const long idx = (long)r * 64 + lane;

    if (mode < 2) {
        float m = fmaxf(fmaxf(fabsf(hx), fabsf(hy)), fmaxf(fabsf(hz), fabsf(hw)));
        #pragma unroll
        for (int off = 32; off; off >>= 1) m = fmaxf(m, __shfl_xor(m, off));
        const float mg  = fmaxf(m, 1e-30f);
        const float inv = 127.0f / mg;
        const unsigned int u0 = (unsigned int)(int)rintf(fmaf(hx, inv, 128.0f));
        const unsigned int u1 = (unsigned int)(int)rintf(fmaf(hy, inv, 128.0f));
        const unsigned int u2 = (unsigned int)(int)rintf(fmaf(hz, inv, 128.0f));
        const unsigned int u3 = (unsigned int)(int)rintf(fmaf(hw, inv, 128.0f));
        ((unsigned int*)q_out)[idx] = u0 | (u1 << 8) | (u2 << 16) | (u3 << 24);
        if (lane == 0) s_out[r] = mg * (1.0f / 127.0f);

        const float inv4 = 7.0f / mg;
        const unsigned int n0 = ((unsigned int)((int)rintf(hx * inv4) + 8)) & 15u;
        const unsigned int n1 = ((unsigned int)((int)rintf(hy * inv4) + 8)) & 15u;
        const unsigned int n2 = ((unsigned int)((int)rintf(hz * inv4) + 8)) & 15u;
        const unsigned int n3 = ((unsigned int)((int)rintf(hw * inv4) + 8)) & 15u;
        q4_out[idx] = (unsigned short)(n0 | (n1 << 4) | (n2 << 8) | (n3 << 12));
        if (lane == 0) s4_out[r] = mg * (1.0f / 7.0f);
    } else {
        const unsigned int g0 = ((const unsigned int*)q0p)[idx];
        const unsigned int g1 = ((const unsigned int*)q1p)[idx];
        const unsigned int g2 = ((const unsigned int*)q2p)[idx];
        const float sc0 = s0p[r], sc1 = s1p[r], sc2 = s2p[r];
        float4 o;
        o.x = 0.25f * (((float)(g0 & 0xff)         - 128.f) * sc0
                     + ((float)(g1 & 0xff)         - 128.f) * sc1
                     + ((float)(g2 & 0xff)         - 128.f) * sc2 + hx);
        o.y = 0.25f * (((float)((g0 >> 8) & 0xff)  - 128.f) * sc0
                     + ((float)((g1 >> 8) & 0xff)  - 128.f) * sc1
                     + ((float)((g2 >> 8) & 0xff)  - 128.f) * sc2 + hy);
        o.z = 0.25f * (((float)((g0 >> 16) & 0xff) - 128.f) * sc0
                     + ((float)((g1 >> 16) & 0xff) - 128.f) * sc1
                     + ((float)((g2 >> 16) & 0xff) - 128.f) * sc2 + hz);
        o.w = 0.25f * (((float)(g0 >> 24)          - 128.f) * sc0
                     + ((float)(g1 >> 24)          - 128.f) * sc1
                     + ((float)(g2 >> 24)          - 128.f) * sc2 + hw);
        ((float4*)out)[idx] = o;
    }
}

extern "C" void kernel_launch(void* const* d_in, const int* in_sizes, int n_in,
                              void* d_out, int out_size, void* d_ws, size_t ws_size,
                              hipStream_t stream) {
    const float* x    = (const float*)d_in[0];
    const float* vals = (const float*)d_in[1];
    const int*   row  = (const int*)d_in[2];
    const int*   col  = (const int*)d_in[3];
    float* out = (float*)d_out;

    const int N = in_sizes[0] / D_FEAT;   // 100000
    const int E = in_sizes[1];            // 1600000

    // workspace: row_ptr | xq | sx | q1 | s1 | q2 | s2 | q1n | s1n | q2n | s2n
    auto align1k = [](size_t v) { return (v + 1023) & ~(size_t)1023; };
    const size_t rp_bytes = align1k((size_t)(N + 1) * sizeof(int));
    const size_t qbytes   = align1k((size_t)N * D_FEAT);               // int8 rows
    const size_t q4bytes  = align1k((size_t)N * D_FEAT / 2);           // int4 rows
    const size_t sbytes   = align1k((size_t)N * sizeof(float));
    char* ws = (char*)d_ws;
    int*            row_ptr = (int*)ws;            ws += rp_bytes;
    unsigned char*  xq  = (unsigned char*)ws;      ws += qbytes;
    float*          sx  = (float*)ws;              ws += sbytes;
    unsigned char*  q1  = (unsigned char*)ws;      ws += qbytes;
    float*          s1  = (float*)ws;              ws += sbytes;
    unsigned char*  q2  = (unsigned char*)ws;      ws += qbytes;
    float*          s2  = (float*)ws;              ws += sbytes;
    unsigned char*  q1n = (unsigned char*)ws;      ws += q4bytes;
    float*          s1n = (float*)ws;              ws += sbytes;
    unsigned char*  q2n = (unsigned char*)ws;      ws += q4bytes;
    float*          s2n = (float*)ws;

    // 1. CSR offsets
    {
        const int threads = 256;
        const int blocks = (E + 1 + threads - 1) / threads;
        build_row_ptr_kernel<<<blocks, threads, 0, stream>>>(row, row_ptr, E, N);
    }

    const int blocks = (N + 3) / 4;  // one wave per row, 4 waves per block

    // 2. quantize x (layer-0 int8 gather table + combine term)
    quant_rows_kernel<<<blocks, 256, 0, stream>>>(x, xq, sx, N);

    // 3. three fused layers
    // L0 (int8 gather): h1 -> q1/s1 (int8) + q1n/s1n (int4)
    spmm_q_kernel<<<blocks, 256, 0, stream>>>(xq, sx, vals, col, row_ptr,
                                              q1, s1, (unsigned short*)q1n, s1n, N);
    // L1 (int4 gather): h2 -> q2/s2 (int8) + q2n/s2n (int4)
    spmm_q4_kernel<<<blocks, 256, 0, stream>>>(q1n, s1n, vals, col, row_ptr,
                                               q2, s2, (unsigned short*)q2n, s2n,
                                               xq, sx, q1, s1, q2, s2, out, N, 0);
    // L2 (int4 gather + combine): out = 0.25*(x + h1 + h2 + h3)
    spmm_q4_kernel<<<blocks, 256, 0, stream>>>(q2n, s2n, vals, col, row_ptr,
                                               q2, s2, (unsigned short*)q2n, s2n,
                                               xq, sx, q1, s1, q2, s2, out, N, 2);
}